// Round 2
// 541.132 us; speedup vs baseline: 1.2326x; 1.2326x over previous
//
#include <hip/hip_runtime.h>
#include <hip/hip_bf16.h>

#define EMB_D 128
#define BSH 9          // rows per coarse bucket = 512
#define MAXBUCK 512    // nbuck = ceil(N/512) must be <= 512 (N <= 262144)
#define CHUNKP 4096    // edges per partition block

__device__ __forceinline__ float bf16_raw_to_f(unsigned short h) {
    return __uint_as_float(((unsigned int)h) << 16);
}
__device__ __forceinline__ unsigned short f_to_bf16_raw(float f) {  // RNE
    unsigned int u = __float_as_uint(f);
    return (unsigned short)((u + 0x7FFFu + ((u >> 16) & 1u)) >> 16);
}
__device__ __forceinline__ unsigned int pack_bf16x2(float lo, float hi) {
    return (unsigned int)f_to_bf16_raw(lo) | ((unsigned int)f_to_bf16_raw(hi) << 16);
}
__device__ __forceinline__ float sane(float v) {
    return (v == v && fabsf(v) < 256.0f) ? v : 0.0f;
}
__device__ __forceinline__ float load_f(const void* p, int isf32, size_t idx) {
    return isf32 ? ((const float*)p)[idx]
                 : bf16_raw_to_f(((const unsigned short*)p)[idx]);
}

// flags[a]=1 if array a is stored fp32, 0 if bf16 (insurance; expect all 1).
__global__ void k_detect(const unsigned short* __restrict__ ue,
                         const unsigned short* __restrict__ ie,
                         const unsigned short* __restrict__ ev,
                         int* __restrict__ flags) {
    int a = blockIdx.x;
    const unsigned short* p = (a == 0) ? ue : (a == 1) ? ie : ev;
    int lane = threadIdx.x;
    int cnt = 0;
    #pragma unroll
    for (int k = 0; k < 16; ++k) {
        float v = bf16_raw_to_f(p[k * 64 + lane]);
        if (!(fabsf(v) < 1.0f)) cnt++;
    }
    #pragma unroll
    for (int off = 32; off > 0; off >>= 1)
        cnt += __shfl_down(cnt, off, 64);
    if (lane == 0) flags[a] = (cnt > 64) ? 1 : 0;
}

// Canonical bf16 table A[N,128] = concat(ue, ie). 4 elems/thread.
__global__ void k_build_emb(const void* __restrict__ ue, const void* __restrict__ ie,
                            const int* __restrict__ flags,
                            unsigned short* __restrict__ A, long nuf, long total) {
    long i = ((long)blockIdx.x * blockDim.x + threadIdx.x) * 4;
    if (i >= total) return;
    int a = (i < nuf) ? 0 : 1;
    const void* src = (a == 0) ? ue : ie;
    long off = (a == 0) ? i : (i - nuf);
    ushort4 o;
    if (flags[a]) {
        float4 t = *(((const float4*)src) + (off >> 2));
        o.x = f_to_bf16_raw(sane(t.x)); o.y = f_to_bf16_raw(sane(t.y));
        o.z = f_to_bf16_raw(sane(t.z)); o.w = f_to_bf16_raw(sane(t.w));
    } else {
        o = *(((const ushort4*)src) + (off >> 2));
    }
    *(ushort4*)(A + i) = o;
}

// Layer-0 gather (fp32 from ORIGINAL inputs) into accumulators.
__global__ void k_init_acc(const void* __restrict__ ue, const void* __restrict__ ie,
                           const int* __restrict__ flags,
                           const int* __restrict__ user, const int* __restrict__ pos,
                           const int* __restrict__ neg, int NU, int NI,
                           float* __restrict__ uacc, float* __restrict__ pacc,
                           float* __restrict__ nacc, float* __restrict__ regp) {
    __shared__ float sred[2];
    int b = blockIdx.x;
    int d = threadIdx.x;   // 0..127
    int ui = min(max(user[b], 0), NU - 1);
    int pi = min(max(pos[b],  0), NI - 1);
    int ni = min(max(neg[b],  0), NI - 1);
    int f0 = flags[0], f1 = flags[1];
    float u = sane(load_f(ue, f0, (size_t)ui * EMB_D + d));
    float p = sane(load_f(ie, f1, (size_t)pi * EMB_D + d));
    float n = sane(load_f(ie, f1, (size_t)ni * EMB_D + d));
    size_t o = (size_t)b * EMB_D + d;
    uacc[o] = u;
    pacc[o] = p;
    nacc[o] = n;
    float s = fabsf(u) + fabsf(p) + fabsf(n);
    #pragma unroll
    for (int off = 32; off > 0; off >>= 1)
        s += __shfl_down(s, off, 64);
    if ((d & 63) == 0) sred[d >> 6] = s;
    __syncthreads();
    if (d == 0) regp[b] = sred[0] + sred[1];
}

// Reduce regp[B] -> reg[0]. Single block.
__global__ void k_reduce_reg(const float* __restrict__ regp, float* __restrict__ reg, int B) {
    __shared__ float ss[256];
    int t = threadIdx.x;
    float s = 0.0f;
    for (int i = t; i < B; i += 256) s += regp[i];
    ss[t] = s;
    __syncthreads();
    for (int off = 128; off > 0; off >>= 1) {
        if (t < off) ss[t] += ss[t + off];
        __syncthreads();
    }
    if (t == 0) reg[0] = ss[0];
}

// ---------- CSR build, transaction-efficient two-level partition ----------

// Pass A: per-block LDS histogram over coarse buckets (row >> BSH).
// bcnt layout is bin-major: bcnt[bin * NB + block]. No global atomics.
__global__ __launch_bounds__(256) void k_part_count(const int* __restrict__ erow,
        int* __restrict__ bcnt, int E, int N, int nbuck, int NB) {
    __shared__ int lh[MAXBUCK];
    int b = blockIdx.x, t = threadIdx.x;
    for (int i = t; i < MAXBUCK; i += 256) lh[i] = 0;
    __syncthreads();
    int beg = b * CHUNKP;
    int cnt = min(CHUNKP, E - beg);
    for (int p = t; p < cnt; p += 256) {
        int r = min(max(erow[beg + p], 0), N - 1);
        atomicAdd(&lh[r >> BSH], 1);
    }
    __syncthreads();
    for (int i = t; i < nbuck; i += 256) bcnt[(long)i * NB + b] = lh[i];
}

// Generic 3-phase exclusive scan over int array a[L] (in place).
__global__ void k_gscan1(const int* __restrict__ a, int* __restrict__ bsums, int L) {
    __shared__ int ss[256];
    int t = threadIdx.x;
    int base = blockIdx.x * 1024 + t * 4;
    int s = 0;
    #pragma unroll
    for (int j = 0; j < 4; ++j) {
        int idx = base + j;
        if (idx < L) s += a[idx];
    }
    ss[t] = s;
    __syncthreads();
    for (int off = 128; off > 0; off >>= 1) {
        if (t < off) ss[t] += ss[t + off];
        __syncthreads();
    }
    if (t == 0) bsums[blockIdx.x] = ss[0];
}

__global__ void k_gscan2(const int* __restrict__ bsums, int* __restrict__ boffs,
                         int nb, int* __restrict__ rowptrN) {
    __shared__ int ss[256];
    int t = threadIdx.x;
    int s = (t < nb) ? bsums[t] : 0;
    ss[t] = s;
    __syncthreads();
    for (int off = 1; off < 256; off <<= 1) {
        int v = (t >= off) ? ss[t - off] : 0;
        __syncthreads();
        ss[t] += v;
        __syncthreads();
    }
    if (t < nb) boffs[t] = ss[t] - s;       // exclusive
    if (t == 255) *rowptrN = ss[255];       // total E -> row_ptr[N]
}

__global__ void k_gscan3(int* __restrict__ a, const int* __restrict__ boffs, int L) {
    __shared__ int ss[256];
    int t = threadIdx.x;
    int base = blockIdx.x * 1024 + t * 4;
    int c[4];
    int s = 0;
    #pragma unroll
    for (int j = 0; j < 4; ++j) {
        int idx = base + j;
        c[j] = (idx < L) ? a[idx] : 0;
        s += c[j];
    }
    ss[t] = s;
    __syncthreads();
    for (int off = 1; off < 256; off <<= 1) {
        int v = (t >= off) ? ss[t - off] : 0;
        __syncthreads();
        ss[t] += v;
        __syncthreads();
    }
    int run = boffs[blockIdx.x] + ss[t] - s;
    #pragma unroll
    for (int j = 0; j < 4; ++j) {
        int idx = base + j;
        if (idx < L) a[idx] = run;
        run += c[j];
    }
}

// Pass B: each block counting-sorts its CHUNKP edges by bucket in LDS and
// streams 8B records {row, (col<<14)|val14} to the globally partitioned
// position. Writes are coalesced runs; no global atomics.
__global__ __launch_bounds__(256) void k_part_scatter(
        const int* __restrict__ erow, const int* __restrict__ ecol,
        const void* __restrict__ eval, const int* __restrict__ flags,
        const int* __restrict__ boff, uint2* __restrict__ part,
        int E, int N, int nbuck, int NB) {
    __shared__ uint2 lrec[CHUNKP];            // 32 KB
    __shared__ unsigned short lidx[CHUNKP];   // 8 KB
    __shared__ int hist[MAXBUCK];             // 2 KB (hist -> cursor -> delta)
    __shared__ int bstart[MAXBUCK];           // 2 KB
    __shared__ int ss[256];
    int b = blockIdx.x, t = threadIdx.x;
    int beg = b * CHUNKP;
    int cnt = min(CHUNKP, E - beg);
    for (int i = t; i < MAXBUCK; i += 256) hist[i] = 0;
    __syncthreads();
    int f2 = flags[2];
    for (int p = t; p < cnt; p += 256) {
        int e = beg + p;
        int r = min(max(erow[e], 0), N - 1);
        int c = min(max(ecol[e], 0), N - 1);
        float v = sane(load_f(eval, f2, e));
        if (v < 0.0f) v = 0.0f;
        unsigned int u = __float_as_uint(v);
        unsigned int vb = ((u + 0x10000u) >> 17) & 0x3FFFu;   // exp8 + man6
        lrec[p] = make_uint2((unsigned int)r, ((unsigned int)c << 14) | vb);
        atomicAdd(&hist[r >> BSH], 1);
    }
    __syncthreads();
    // exclusive scan of hist[0..MAXBUCK) -> bstart (2 bins per thread)
    int c0 = hist[2 * t], c1 = hist[2 * t + 1];
    int s = c0 + c1;
    ss[t] = s;
    __syncthreads();
    for (int off = 1; off < 256; off <<= 1) {
        int v = (t >= off) ? ss[t - off] : 0;
        __syncthreads();
        ss[t] += v;
        __syncthreads();
    }
    int eb = ss[t] - s;
    bstart[2 * t] = eb;
    bstart[2 * t + 1] = eb + c0;
    hist[2 * t] = eb;              // cursor = bstart
    hist[2 * t + 1] = eb + c0;
    __syncthreads();
    // rank: lidx[sorted_pos] = arrival index
    for (int p = t; p < cnt; p += 256) {
        int bin = (int)(lrec[p].x >> BSH);
        int pos = atomicAdd(&hist[bin], 1);
        lidx[pos] = (unsigned short)p;
    }
    __syncthreads();
    // delta[bin] = global block-bin offset - local bin start (reuse hist)
    for (int i = t; i < nbuck; i += 256)
        hist[i] = boff[(long)i * NB + b] - bstart[i];
    __syncthreads();
    // stream out in bucket-sorted order -> coalesced runs
    for (int p = t; p < cnt; p += 256) {
        uint2 rec = lrec[lidx[p]];
        int bin = (int)(rec.x >> BSH);
        part[hist[bin] + p] = rec;
    }
}

// Pass C: one block per bucket (<=512 rows, L2-resident window).
// LDS histogram + LDS scan -> row_ptr; LDS-atomic cursor -> sedge.
__global__ __launch_bounds__(256) void k_build_csr(
        const uint2* __restrict__ part, const int* __restrict__ boff,
        int* __restrict__ row_ptr, unsigned int* __restrict__ sedge,
        int E, int N, int NB, int nbuck) {
    __shared__ int rcnt[512];
    __shared__ int rstart[512];
    __shared__ int rcur[512];
    __shared__ int ss[256];
    int bin = blockIdx.x, t = threadIdx.x;
    int base = boff[(long)bin * NB];
    int next = (bin + 1 < nbuck) ? boff[(long)(bin + 1) * NB] : E;
    int cnt = next - base;
    int r0 = bin << BSH;
    int nrows = min(512, N - r0);
    rcnt[2 * t] = 0; rcnt[2 * t + 1] = 0;
    __syncthreads();
    for (int i = t; i < cnt; i += 256)
        atomicAdd(&rcnt[part[base + i].x - r0], 1);
    __syncthreads();
    int c0 = rcnt[2 * t], c1 = rcnt[2 * t + 1];
    int s = c0 + c1;
    ss[t] = s;
    __syncthreads();
    for (int off = 1; off < 256; off <<= 1) {
        int v = (t >= off) ? ss[t - off] : 0;
        __syncthreads();
        ss[t] += v;
        __syncthreads();
    }
    int eb = ss[t] - s;
    rstart[2 * t] = eb; rstart[2 * t + 1] = eb + c0;
    rcur[2 * t]   = eb; rcur[2 * t + 1]   = eb + c0;
    __syncthreads();
    for (int j = t; j < nrows; j += 256)
        row_ptr[r0 + j] = base + rstart[j];
    for (int i = t; i < cnt; i += 256) {
        uint2 rec = part[base + i];
        int pos = atomicAdd(&rcur[rec.x - r0], 1);
        sedge[base + pos] = rec.y;
    }
}

// ---------- SpMM + tail (unchanged) ----------

// Atomic-free SpMM: one wave per dst row; eight 8-lane subgroups each process
// every 8th edge; lane covers 32B (16 elems) via two uint4 loads.
__global__ void k_spmm_csr(const unsigned short* __restrict__ src,
                           unsigned short* __restrict__ dst,
                           const int* __restrict__ row_ptr,
                           const unsigned int* __restrict__ sedge, int N) {
    int row = blockIdx.x * (blockDim.x >> 6) + (threadIdx.x >> 6);
    if (row >= N) return;
    int lane = threadIdx.x & 63;
    int sub = lane >> 3;         // 0..7: edge phase
    int sl  = lane & 7;          // covers bytes [32*sl, 32*sl+31] of the row
    int beg = row_ptr[row], end = row_ptr[row + 1];
    float a[16];
    #pragma unroll
    for (int j = 0; j < 16; ++j) a[j] = 0.0f;
    const char* sbase = (const char*)src;
    for (int i = beg + sub; i < end; i += 8) {
        unsigned int se = sedge[i];
        float v = __uint_as_float((se & 0x3FFFu) << 17);
        size_t off = (size_t)(se >> 14) * (EMB_D * 2) + sl * 32;
        uint4 h0 = *(const uint4*)(sbase + off);
        uint4 h1 = *(const uint4*)(sbase + off + 16);
        a[0]  += v * __uint_as_float(h0.x << 16);
        a[1]  += v * __uint_as_float(h0.x & 0xFFFF0000u);
        a[2]  += v * __uint_as_float(h0.y << 16);
        a[3]  += v * __uint_as_float(h0.y & 0xFFFF0000u);
        a[4]  += v * __uint_as_float(h0.z << 16);
        a[5]  += v * __uint_as_float(h0.z & 0xFFFF0000u);
        a[6]  += v * __uint_as_float(h0.w << 16);
        a[7]  += v * __uint_as_float(h0.w & 0xFFFF0000u);
        a[8]  += v * __uint_as_float(h1.x << 16);
        a[9]  += v * __uint_as_float(h1.x & 0xFFFF0000u);
        a[10] += v * __uint_as_float(h1.y << 16);
        a[11] += v * __uint_as_float(h1.y & 0xFFFF0000u);
        a[12] += v * __uint_as_float(h1.z << 16);
        a[13] += v * __uint_as_float(h1.z & 0xFFFF0000u);
        a[14] += v * __uint_as_float(h1.w << 16);
        a[15] += v * __uint_as_float(h1.w & 0xFFFF0000u);
    }
    #pragma unroll
    for (int j = 0; j < 16; ++j) {
        a[j] += __shfl_xor(a[j], 8, 64);
        a[j] += __shfl_xor(a[j], 16, 64);
        a[j] += __shfl_xor(a[j], 32, 64);
    }
    if (sub == 0) {
        uint4 o0, o1;
        o0.x = pack_bf16x2(a[0],  a[1]);
        o0.y = pack_bf16x2(a[2],  a[3]);
        o0.z = pack_bf16x2(a[4],  a[5]);
        o0.w = pack_bf16x2(a[6],  a[7]);
        o1.x = pack_bf16x2(a[8],  a[9]);
        o1.y = pack_bf16x2(a[10], a[11]);
        o1.z = pack_bf16x2(a[12], a[13]);
        o1.w = pack_bf16x2(a[14], a[15]);
        char* dbase = (char*)dst + (size_t)row * (EMB_D * 2) + sl * 32;
        *(uint4*)dbase = o0;
        *(uint4*)(dbase + 16) = o1;
    }
}

// Accumulate this layer's rows (bf16 table) at batch indices.
__global__ void k_gather_add(const unsigned short* __restrict__ L,
                             const int* __restrict__ user, const int* __restrict__ pos,
                             const int* __restrict__ neg,
                             float* __restrict__ uacc, float* __restrict__ pacc,
                             float* __restrict__ nacc, int NU, int NI) {
    int b = blockIdx.x;
    int d = threadIdx.x;   // 0..127
    int ui = min(max(user[b], 0), NU - 1);
    int pi = min(max(pos[b],  0), NI - 1);
    int ni = min(max(neg[b],  0), NI - 1);
    size_t o = (size_t)b * EMB_D + d;
    uacc[o] += bf16_raw_to_f(L[(size_t)ui * EMB_D + d]);
    pacc[o] += bf16_raw_to_f(L[((size_t)NU + pi) * EMB_D + d]);
    nacc[o] += bf16_raw_to_f(L[((size_t)NU + ni) * EMB_D + d]);
}

// One wave per batch element: dots, softplus, + reg; fp32 store.
__global__ void k_final(const float* __restrict__ uacc, const float* __restrict__ pacc,
                        const float* __restrict__ nacc, const float* __restrict__ reg,
                        float* __restrict__ out) {
    int b = blockIdx.x;
    int l = threadIdx.x;   // 0..63
    const float2* u2 = (const float2*)(uacc + (size_t)b * EMB_D);
    const float2* p2 = (const float2*)(pacc + (size_t)b * EMB_D);
    const float2* n2 = (const float2*)(nacc + (size_t)b * EMB_D);
    float2 u = u2[l], p = p2[l], n = n2[l];
    float ps = u.x * p.x + u.y * p.y;
    float ns = u.x * n.x + u.y * n.y;
    #pragma unroll
    for (int off = 32; off > 0; off >>= 1) {
        ps += __shfl_down(ps, off, 64);
        ns += __shfl_down(ns, off, 64);
    }
    if (l == 0) {
        // latents are acc/4 -> scores scale by 1/16
        float x = (ns - ps) * 0.0625f;
        float sp = fmaxf(x, 0.0f) + log1pf(expf(-fabsf(x)));
        out[b] = sp + 1e-4f * reg[0];
    }
}

extern "C" void kernel_launch(void* const* d_in, const int* in_sizes, int n_in,
                              void* d_out, int out_size, void* d_ws, size_t ws_size,
                              hipStream_t stream) {
    const void* ue   = d_in[0];
    const void* ie   = d_in[1];
    const int*  erow = (const int*)d_in[2];
    const int*  ecol = (const int*)d_in[3];
    const void* ev   = d_in[4];
    const int*  user = (const int*)d_in[5];
    const int*  pos  = (const int*)d_in[6];
    const int*  neg  = (const int*)d_in[7];

    int NU = in_sizes[0] / EMB_D;        // 100000
    int NI = in_sizes[1] / EMB_D;        // 50000
    int N  = NU + NI;                    // 150000
    int E  = in_sizes[2];                // 2000000
    int B  = in_sizes[5];                // 8192

    int nbuck = (N + ((1 << BSH) - 1)) >> BSH;   // 293 (must be <= MAXBUCK)
    int NBp   = (E + CHUNKP - 1) / CHUNKP;       // 489 partition blocks
    int L     = nbuck * NBp;                     // 143277
    int nbL   = (L + 1023) / 1024;               // 140 (<= 256)

    // Workspace layout (all 16B-aligned):
    size_t BACC = (size_t)B * EMB_D * sizeof(float);          // 4 MB
    size_t NT   = (size_t)N * EMB_D * sizeof(unsigned short); // 38.4 MB
    size_t NI4  = ((size_t)(N + 1) * sizeof(int) + 15) & ~15ull;
    size_t L4   = ((size_t)L * sizeof(int) + 15) & ~15ull;
    char* w = (char*)d_ws;
    int*   flags   = (int*)w;                        // 3 ints
    float* reg     = (float*)(w + 64);               // 1 float
    float* uacc    = (float*)(w + 256);
    float* pacc    = (float*)(w + 256 + BACC);
    float* nacc    = (float*)(w + 256 + 2 * BACC);
    char*  q       = w + 256 + 3 * BACC;
    float* regp    = (float*)q;             q += (size_t)B * sizeof(float);
    int*   row_ptr = (int*)q;               q += NI4;
    uint2* part    = (uint2*)q;             q += (size_t)E * sizeof(uint2);   // 16 MB
    int*   bcnt    = (int*)q;               q += L4;                          // 573 KB
    int*   bsums   = (int*)q;               q += 1024;
    int*   boffs   = (int*)q;               q += 1024;
    unsigned int* sedge = (unsigned int*)q; q += (size_t)E * sizeof(unsigned int); // 8 MB
    unsigned short* Atab = (unsigned short*)q;  q += NT;
    unsigned short* Btab = (unsigned short*)q;
    // total ~114 MB (prev session proved ws >= 166 MB)

    long total = (long)N * EMB_D;        // 19.2M
    long nuf   = (long)NU * EMB_D;
    const int thr = 256;
    float* out = (float*)d_out;

    k_detect<<<3, 64, 0, stream>>>((const unsigned short*)ue, (const unsigned short*)ie,
                                   (const unsigned short*)ev, flags);
    k_build_emb<<<(unsigned)((total / 4 + thr - 1) / thr), thr, 0, stream>>>(ue, ie, flags, Atab, nuf, total);
    k_init_acc<<<B, EMB_D, 0, stream>>>(ue, ie, flags, user, pos, neg, NU, NI,
                                        uacc, pacc, nacc, regp);
    k_reduce_reg<<<1, 256, 0, stream>>>(regp, reg, B);

    // CSR build: two-level LDS partition, no global atomics.
    k_part_count<<<NBp, 256, 0, stream>>>(erow, bcnt, E, N, nbuck, NBp);
    k_gscan1<<<nbL, 256, 0, stream>>>(bcnt, bsums, L);
    k_gscan2<<<1, 256, 0, stream>>>(bsums, boffs, nbL, row_ptr + N);
    k_gscan3<<<nbL, 256, 0, stream>>>(bcnt, boffs, L);
    k_part_scatter<<<NBp, 256, 0, stream>>>(erow, ecol, ev, flags, bcnt, part, E, N, nbuck, NBp);
    k_build_csr<<<nbuck, 256, 0, stream>>>(part, bcnt, row_ptr, sedge, E, N, NBp, nbuck);

    int rows_per_block = thr / 64;                       // 4
    int sgrid = (N + rows_per_block - 1) / rows_per_block;  // 37500

    // Layer 1: Atab -> Btab
    k_spmm_csr<<<sgrid, thr, 0, stream>>>(Atab, Btab, row_ptr, sedge, N);
    k_gather_add<<<B, EMB_D, 0, stream>>>(Btab, user, pos, neg, uacc, pacc, nacc, NU, NI);
    // Layer 2: Btab -> Atab
    k_spmm_csr<<<sgrid, thr, 0, stream>>>(Btab, Atab, row_ptr, sedge, N);
    k_gather_add<<<B, EMB_D, 0, stream>>>(Atab, user, pos, neg, uacc, pacc, nacc, NU, NI);
    // Layer 3: Atab -> Btab
    k_spmm_csr<<<sgrid, thr, 0, stream>>>(Atab, Btab, row_ptr, sedge, N);
    k_gather_add<<<B, EMB_D, 0, stream>>>(Btab, user, pos, neg, uacc, pacc, nacc, NU, NI);

    k_final<<<B, 64, 0, stream>>>(uacc, pacc, nacc, reg, out);
}

// Round 3
// 467.508 us; speedup vs baseline: 1.4267x; 1.1575x over previous
//
#include <hip/hip_runtime.h>
#include <hip/hip_bf16.h>

#define EMB_D 128
#define BSH 9          // rows per coarse bucket = 512
#define MAXBUCK 512    // nbuck = ceil(N/512) must be <= 512 (N <= 262144)
#define CHUNKP 4096    // edges per partition block

__device__ __forceinline__ float bf16_raw_to_f(unsigned short h) {
    return __uint_as_float(((unsigned int)h) << 16);
}
__device__ __forceinline__ unsigned short f_to_bf16_raw(float f) {  // RNE
    unsigned int u = __float_as_uint(f);
    return (unsigned short)((u + 0x7FFFu + ((u >> 16) & 1u)) >> 16);
}
__device__ __forceinline__ unsigned int pack_bf16x2(float lo, float hi) {
    return (unsigned int)f_to_bf16_raw(lo) | ((unsigned int)f_to_bf16_raw(hi) << 16);
}
__device__ __forceinline__ float sane(float v) {
    return (v == v && fabsf(v) < 256.0f) ? v : 0.0f;
}
__device__ __forceinline__ float load_f(const void* p, int isf32, size_t idx) {
    return isf32 ? ((const float*)p)[idx]
                 : bf16_raw_to_f(((const unsigned short*)p)[idx]);
}

// flags[a]=1 if array a is stored fp32, 0 if bf16 (insurance; expect all 1).
__global__ void k_detect(const unsigned short* __restrict__ ue,
                         const unsigned short* __restrict__ ie,
                         const unsigned short* __restrict__ ev,
                         int* __restrict__ flags) {
    int a = blockIdx.x;
    const unsigned short* p = (a == 0) ? ue : (a == 1) ? ie : ev;
    int lane = threadIdx.x;
    int cnt = 0;
    #pragma unroll
    for (int k = 0; k < 16; ++k) {
        float v = bf16_raw_to_f(p[k * 64 + lane]);
        if (!(fabsf(v) < 1.0f)) cnt++;
    }
    #pragma unroll
    for (int off = 32; off > 0; off >>= 1)
        cnt += __shfl_down(cnt, off, 64);
    if (lane == 0) flags[a] = (cnt > 64) ? 1 : 0;
}

// Canonical bf16 table A[N,128] = concat(ue, ie). 4 elems/thread.
__global__ void k_build_emb(const void* __restrict__ ue, const void* __restrict__ ie,
                            const int* __restrict__ flags,
                            unsigned short* __restrict__ A, long nuf, long total) {
    long i = ((long)blockIdx.x * blockDim.x + threadIdx.x) * 4;
    if (i >= total) return;
    int a = (i < nuf) ? 0 : 1;
    const void* src = (a == 0) ? ue : ie;
    long off = (a == 0) ? i : (i - nuf);
    ushort4 o;
    if (flags[a]) {
        float4 t = *(((const float4*)src) + (off >> 2));
        o.x = f_to_bf16_raw(sane(t.x)); o.y = f_to_bf16_raw(sane(t.y));
        o.z = f_to_bf16_raw(sane(t.z)); o.w = f_to_bf16_raw(sane(t.w));
    } else {
        o = *(((const ushort4*)src) + (off >> 2));
    }
    *(ushort4*)(A + i) = o;
}

// Layer-0 gather (fp32 from ORIGINAL inputs) into accumulators.
__global__ void k_init_acc(const void* __restrict__ ue, const void* __restrict__ ie,
                           const int* __restrict__ flags,
                           const int* __restrict__ user, const int* __restrict__ pos,
                           const int* __restrict__ neg, int NU, int NI,
                           float* __restrict__ uacc, float* __restrict__ pacc,
                           float* __restrict__ nacc, float* __restrict__ regp) {
    __shared__ float sred[2];
    int b = blockIdx.x;
    int d = threadIdx.x;   // 0..127
    int ui = min(max(user[b], 0), NU - 1);
    int pi = min(max(pos[b],  0), NI - 1);
    int ni = min(max(neg[b],  0), NI - 1);
    int f0 = flags[0], f1 = flags[1];
    float u = sane(load_f(ue, f0, (size_t)ui * EMB_D + d));
    float p = sane(load_f(ie, f1, (size_t)pi * EMB_D + d));
    float n = sane(load_f(ie, f1, (size_t)ni * EMB_D + d));
    size_t o = (size_t)b * EMB_D + d;
    uacc[o] = u;
    pacc[o] = p;
    nacc[o] = n;
    float s = fabsf(u) + fabsf(p) + fabsf(n);
    #pragma unroll
    for (int off = 32; off > 0; off >>= 1)
        s += __shfl_down(s, off, 64);
    if ((d & 63) == 0) sred[d >> 6] = s;
    __syncthreads();
    if (d == 0) regp[b] = sred[0] + sred[1];
}

// Reduce regp[B] -> reg[0]. Single block.
__global__ void k_reduce_reg(const float* __restrict__ regp, float* __restrict__ reg, int B) {
    __shared__ float ss[256];
    int t = threadIdx.x;
    float s = 0.0f;
    for (int i = t; i < B; i += 256) s += regp[i];
    ss[t] = s;
    __syncthreads();
    for (int off = 128; off > 0; off >>= 1) {
        if (t < off) ss[t] += ss[t + off];
        __syncthreads();
    }
    if (t == 0) reg[0] = ss[0];
}

// ---------- CSR build, transaction-efficient two-level partition ----------

// Pass A: per-block LDS histogram over coarse buckets (row >> BSH).
// bcnt layout is bin-major: bcnt[bin * NB + block]. No global atomics.
__global__ __launch_bounds__(256) void k_part_count(const int* __restrict__ erow,
        int* __restrict__ bcnt, int E, int N, int nbuck, int NB) {
    __shared__ int lh[MAXBUCK];
    int b = blockIdx.x, t = threadIdx.x;
    for (int i = t; i < MAXBUCK; i += 256) lh[i] = 0;
    __syncthreads();
    int beg = b * CHUNKP;
    int cnt = min(CHUNKP, E - beg);
    for (int p = t; p < cnt; p += 256) {
        int r = min(max(erow[beg + p], 0), N - 1);
        atomicAdd(&lh[r >> BSH], 1);
    }
    __syncthreads();
    for (int i = t; i < nbuck; i += 256) bcnt[(long)i * NB + b] = lh[i];
}

// Generic 3-phase exclusive scan over int array a[L] (in place).
__global__ void k_gscan1(const int* __restrict__ a, int* __restrict__ bsums, int L) {
    __shared__ int ss[256];
    int t = threadIdx.x;
    int base = blockIdx.x * 1024 + t * 4;
    int s = 0;
    #pragma unroll
    for (int j = 0; j < 4; ++j) {
        int idx = base + j;
        if (idx < L) s += a[idx];
    }
    ss[t] = s;
    __syncthreads();
    for (int off = 128; off > 0; off >>= 1) {
        if (t < off) ss[t] += ss[t + off];
        __syncthreads();
    }
    if (t == 0) bsums[blockIdx.x] = ss[0];
}

__global__ void k_gscan2(const int* __restrict__ bsums, int* __restrict__ boffs,
                         int nb, int* __restrict__ rowptrN) {
    __shared__ int ss[256];
    int t = threadIdx.x;
    int s = (t < nb) ? bsums[t] : 0;
    ss[t] = s;
    __syncthreads();
    for (int off = 1; off < 256; off <<= 1) {
        int v = (t >= off) ? ss[t - off] : 0;
        __syncthreads();
        ss[t] += v;
        __syncthreads();
    }
    if (t < nb) boffs[t] = ss[t] - s;       // exclusive
    if (t == 255) *rowptrN = ss[255];       // total E -> row_ptr[N]
}

__global__ void k_gscan3(int* __restrict__ a, const int* __restrict__ boffs, int L) {
    __shared__ int ss[256];
    int t = threadIdx.x;
    int base = blockIdx.x * 1024 + t * 4;
    int c[4];
    int s = 0;
    #pragma unroll
    for (int j = 0; j < 4; ++j) {
        int idx = base + j;
        c[j] = (idx < L) ? a[idx] : 0;
        s += c[j];
    }
    ss[t] = s;
    __syncthreads();
    for (int off = 1; off < 256; off <<= 1) {
        int v = (t >= off) ? ss[t - off] : 0;
        __syncthreads();
        ss[t] += v;
        __syncthreads();
    }
    int run = boffs[blockIdx.x] + ss[t] - s;
    #pragma unroll
    for (int j = 0; j < 4; ++j) {
        int idx = base + j;
        if (idx < L) a[idx] = run;
        run += c[j];
    }
}

// Pass B: each block counting-sorts its CHUNKP edges by bucket in LDS and
// streams 8B records {row, (col<<14)|val14} to the globally partitioned
// position. Writes are coalesced runs; no global atomics.
__global__ __launch_bounds__(256) void k_part_scatter(
        const int* __restrict__ erow, const int* __restrict__ ecol,
        const void* __restrict__ eval, const int* __restrict__ flags,
        const int* __restrict__ boff, uint2* __restrict__ part,
        int E, int N, int nbuck, int NB) {
    __shared__ uint2 lrec[CHUNKP];            // 32 KB
    __shared__ unsigned short lidx[CHUNKP];   // 8 KB
    __shared__ int hist[MAXBUCK];             // 2 KB (hist -> cursor -> delta)
    __shared__ int bstart[MAXBUCK];           // 2 KB
    __shared__ int ss[256];
    int b = blockIdx.x, t = threadIdx.x;
    int beg = b * CHUNKP;
    int cnt = min(CHUNKP, E - beg);
    for (int i = t; i < MAXBUCK; i += 256) hist[i] = 0;
    __syncthreads();
    int f2 = flags[2];
    for (int p = t; p < cnt; p += 256) {
        int e = beg + p;
        int r = min(max(erow[e], 0), N - 1);
        int c = min(max(ecol[e], 0), N - 1);
        float v = sane(load_f(eval, f2, e));
        if (v < 0.0f) v = 0.0f;
        unsigned int u = __float_as_uint(v);
        unsigned int vb = ((u + 0x10000u) >> 17) & 0x3FFFu;   // exp8 + man6
        lrec[p] = make_uint2((unsigned int)r, ((unsigned int)c << 14) | vb);
        atomicAdd(&hist[r >> BSH], 1);
    }
    __syncthreads();
    // exclusive scan of hist[0..MAXBUCK) -> bstart (2 bins per thread)
    int c0 = hist[2 * t], c1 = hist[2 * t + 1];
    int s = c0 + c1;
    ss[t] = s;
    __syncthreads();
    for (int off = 1; off < 256; off <<= 1) {
        int v = (t >= off) ? ss[t - off] : 0;
        __syncthreads();
        ss[t] += v;
        __syncthreads();
    }
    int eb = ss[t] - s;
    bstart[2 * t] = eb;
    bstart[2 * t + 1] = eb + c0;
    hist[2 * t] = eb;              // cursor = bstart
    hist[2 * t + 1] = eb + c0;
    __syncthreads();
    // rank: lidx[sorted_pos] = arrival index
    for (int p = t; p < cnt; p += 256) {
        int bin = (int)(lrec[p].x >> BSH);
        int pos = atomicAdd(&hist[bin], 1);
        lidx[pos] = (unsigned short)p;
    }
    __syncthreads();
    // delta[bin] = global block-bin offset - local bin start (reuse hist)
    for (int i = t; i < nbuck; i += 256)
        hist[i] = boff[(long)i * NB + b] - bstart[i];
    __syncthreads();
    // stream out in bucket-sorted order -> coalesced runs
    for (int p = t; p < cnt; p += 256) {
        uint2 rec = lrec[lidx[p]];
        int bin = (int)(rec.x >> BSH);
        part[hist[bin] + p] = rec;
    }
}

// Pass C: one block per bucket (<=512 rows, L2-resident window).
// LDS histogram + LDS scan -> row_ptr; LDS-atomic cursor -> sedge.
__global__ __launch_bounds__(256) void k_build_csr(
        const uint2* __restrict__ part, const int* __restrict__ boff,
        int* __restrict__ row_ptr, unsigned int* __restrict__ sedge,
        int E, int N, int NB, int nbuck) {
    __shared__ int rcnt[512];
    __shared__ int rstart[512];
    __shared__ int rcur[512];
    __shared__ int ss[256];
    int bin = blockIdx.x, t = threadIdx.x;
    int base = boff[(long)bin * NB];
    int next = (bin + 1 < nbuck) ? boff[(long)(bin + 1) * NB] : E;
    int cnt = next - base;
    int r0 = bin << BSH;
    int nrows = min(512, N - r0);
    rcnt[2 * t] = 0; rcnt[2 * t + 1] = 0;
    __syncthreads();
    for (int i = t; i < cnt; i += 256)
        atomicAdd(&rcnt[part[base + i].x - r0], 1);
    __syncthreads();
    int c0 = rcnt[2 * t], c1 = rcnt[2 * t + 1];
    int s = c0 + c1;
    ss[t] = s;
    __syncthreads();
    for (int off = 1; off < 256; off <<= 1) {
        int v = (t >= off) ? ss[t - off] : 0;
        __syncthreads();
        ss[t] += v;
        __syncthreads();
    }
    int eb = ss[t] - s;
    rstart[2 * t] = eb; rstart[2 * t + 1] = eb + c0;
    rcur[2 * t]   = eb; rcur[2 * t + 1]   = eb + c0;
    __syncthreads();
    for (int j = t; j < nrows; j += 256)
        row_ptr[r0 + j] = base + rstart[j];
    for (int i = t; i < cnt; i += 256) {
        uint2 rec = part[base + i];
        int pos = atomicAdd(&rcur[rec.x - r0], 1);
        sedge[base + pos] = rec.y;
    }
}

// ---------- Frontier marking (backward pruning, bit-exact) ----------

// Zero both flag arrays (2*Npad bytes as ints).
__global__ void k_zero_flags(int* __restrict__ f, int words) {
    int i = blockIdx.x * blockDim.x + threadIdx.x;
    if (i < words) f[i] = 0;
}

// Mark batch nodes into flag3 AND flag2 (idempotent byte stores).
__global__ void k_mark_batch(const int* __restrict__ user, const int* __restrict__ pos,
                             const int* __restrict__ neg, int NU, int NI, int B,
                             unsigned char* __restrict__ flag3,
                             unsigned char* __restrict__ flag2) {
    int b = blockIdx.x * blockDim.x + threadIdx.x;
    if (b >= B) return;
    int ui = min(max(user[b], 0), NU - 1);
    int pi = NU + min(max(pos[b], 0), NI - 1);
    int ni = NU + min(max(neg[b], 0), NI - 1);
    flag3[ui] = 1; flag3[pi] = 1; flag3[ni] = 1;
    flag2[ui] = 1; flag2[pi] = 1; flag2[ni] = 1;
}

// For each flag3 row, mark its in-neighbors (cols) into flag2.
// One thread per row; edges of a row are contiguous in sedge.
__global__ void k_mark_nbrs(const int* __restrict__ row_ptr,
                            const unsigned int* __restrict__ sedge,
                            const unsigned char* __restrict__ flag3,
                            unsigned char* __restrict__ flag2, int N) {
    int r = blockIdx.x * blockDim.x + threadIdx.x;
    if (r >= N || !flag3[r]) return;
    int beg = row_ptr[r], end = row_ptr[r + 1];
    for (int i = beg; i < end; ++i)
        flag2[sedge[i] >> 14] = 1;
}

// ---------- SpMM + tail ----------

// Atomic-free SpMM: one wave per dst row; eight 8-lane subgroups each process
// every 8th edge; lane covers 32B (16 elems) via two uint4 loads.
// If use_skip, rows with skipf[row]==0 are not computed (their dst rows are
// never read downstream).
__global__ void k_spmm_csr(const unsigned short* __restrict__ src,
                           unsigned short* __restrict__ dst,
                           const int* __restrict__ row_ptr,
                           const unsigned int* __restrict__ sedge, int N,
                           const unsigned char* __restrict__ skipf, int use_skip) {
    int row = blockIdx.x * (blockDim.x >> 6) + (threadIdx.x >> 6);
    if (row >= N) return;
    if (use_skip && skipf[row] == 0) return;
    int lane = threadIdx.x & 63;
    int sub = lane >> 3;         // 0..7: edge phase
    int sl  = lane & 7;          // covers bytes [32*sl, 32*sl+31] of the row
    int beg = row_ptr[row], end = row_ptr[row + 1];
    float a[16];
    #pragma unroll
    for (int j = 0; j < 16; ++j) a[j] = 0.0f;
    const char* sbase = (const char*)src;
    for (int i = beg + sub; i < end; i += 8) {
        unsigned int se = sedge[i];
        float v = __uint_as_float((se & 0x3FFFu) << 17);
        size_t off = (size_t)(se >> 14) * (EMB_D * 2) + sl * 32;
        uint4 h0 = *(const uint4*)(sbase + off);
        uint4 h1 = *(const uint4*)(sbase + off + 16);
        a[0]  += v * __uint_as_float(h0.x << 16);
        a[1]  += v * __uint_as_float(h0.x & 0xFFFF0000u);
        a[2]  += v * __uint_as_float(h0.y << 16);
        a[3]  += v * __uint_as_float(h0.y & 0xFFFF0000u);
        a[4]  += v * __uint_as_float(h0.z << 16);
        a[5]  += v * __uint_as_float(h0.z & 0xFFFF0000u);
        a[6]  += v * __uint_as_float(h0.w << 16);
        a[7]  += v * __uint_as_float(h0.w & 0xFFFF0000u);
        a[8]  += v * __uint_as_float(h1.x << 16);
        a[9]  += v * __uint_as_float(h1.x & 0xFFFF0000u);
        a[10] += v * __uint_as_float(h1.y << 16);
        a[11] += v * __uint_as_float(h1.y & 0xFFFF0000u);
        a[12] += v * __uint_as_float(h1.z << 16);
        a[13] += v * __uint_as_float(h1.z & 0xFFFF0000u);
        a[14] += v * __uint_as_float(h1.w << 16);
        a[15] += v * __uint_as_float(h1.w & 0xFFFF0000u);
    }
    #pragma unroll
    for (int j = 0; j < 16; ++j) {
        a[j] += __shfl_xor(a[j], 8, 64);
        a[j] += __shfl_xor(a[j], 16, 64);
        a[j] += __shfl_xor(a[j], 32, 64);
    }
    if (sub == 0) {
        uint4 o0, o1;
        o0.x = pack_bf16x2(a[0],  a[1]);
        o0.y = pack_bf16x2(a[2],  a[3]);
        o0.z = pack_bf16x2(a[4],  a[5]);
        o0.w = pack_bf16x2(a[6],  a[7]);
        o1.x = pack_bf16x2(a[8],  a[9]);
        o1.y = pack_bf16x2(a[10], a[11]);
        o1.z = pack_bf16x2(a[12], a[13]);
        o1.w = pack_bf16x2(a[14], a[15]);
        char* dbase = (char*)dst + (size_t)row * (EMB_D * 2) + sl * 32;
        *(uint4*)dbase = o0;
        *(uint4*)(dbase + 16) = o1;
    }
}

// Accumulate this layer's rows (bf16 table) at batch indices.
__global__ void k_gather_add(const unsigned short* __restrict__ L,
                             const int* __restrict__ user, const int* __restrict__ pos,
                             const int* __restrict__ neg,
                             float* __restrict__ uacc, float* __restrict__ pacc,
                             float* __restrict__ nacc, int NU, int NI) {
    int b = blockIdx.x;
    int d = threadIdx.x;   // 0..127
    int ui = min(max(user[b], 0), NU - 1);
    int pi = min(max(pos[b],  0), NI - 1);
    int ni = min(max(neg[b],  0), NI - 1);
    size_t o = (size_t)b * EMB_D + d;
    uacc[o] += bf16_raw_to_f(L[(size_t)ui * EMB_D + d]);
    pacc[o] += bf16_raw_to_f(L[((size_t)NU + pi) * EMB_D + d]);
    nacc[o] += bf16_raw_to_f(L[((size_t)NU + ni) * EMB_D + d]);
}

// One wave per batch element: dots, softplus, + reg; fp32 store.
__global__ void k_final(const float* __restrict__ uacc, const float* __restrict__ pacc,
                        const float* __restrict__ nacc, const float* __restrict__ reg,
                        float* __restrict__ out) {
    int b = blockIdx.x;
    int l = threadIdx.x;   // 0..63
    const float2* u2 = (const float2*)(uacc + (size_t)b * EMB_D);
    const float2* p2 = (const float2*)(pacc + (size_t)b * EMB_D);
    const float2* n2 = (const float2*)(nacc + (size_t)b * EMB_D);
    float2 u = u2[l], p = p2[l], n = n2[l];
    float ps = u.x * p.x + u.y * p.y;
    float ns = u.x * n.x + u.y * n.y;
    #pragma unroll
    for (int off = 32; off > 0; off >>= 1) {
        ps += __shfl_down(ps, off, 64);
        ns += __shfl_down(ns, off, 64);
    }
    if (l == 0) {
        // latents are acc/4 -> scores scale by 1/16
        float x = (ns - ps) * 0.0625f;
        float sp = fmaxf(x, 0.0f) + log1pf(expf(-fabsf(x)));
        out[b] = sp + 1e-4f * reg[0];
    }
}

extern "C" void kernel_launch(void* const* d_in, const int* in_sizes, int n_in,
                              void* d_out, int out_size, void* d_ws, size_t ws_size,
                              hipStream_t stream) {
    const void* ue   = d_in[0];
    const void* ie   = d_in[1];
    const int*  erow = (const int*)d_in[2];
    const int*  ecol = (const int*)d_in[3];
    const void* ev   = d_in[4];
    const int*  user = (const int*)d_in[5];
    const int*  pos  = (const int*)d_in[6];
    const int*  neg  = (const int*)d_in[7];

    int NU = in_sizes[0] / EMB_D;        // 100000
    int NI = in_sizes[1] / EMB_D;        // 50000
    int N  = NU + NI;                    // 150000
    int E  = in_sizes[2];                // 2000000
    int B  = in_sizes[5];                // 8192

    int nbuck = (N + ((1 << BSH) - 1)) >> BSH;   // 293 (must be <= MAXBUCK)
    int NBp   = (E + CHUNKP - 1) / CHUNKP;       // 489 partition blocks
    int L     = nbuck * NBp;                     // 143277
    int nbL   = (L + 1023) / 1024;               // 140 (<= 256)

    // Workspace layout (all 16B-aligned):
    size_t BACC = (size_t)B * EMB_D * sizeof(float);          // 4 MB
    size_t NT   = (size_t)N * EMB_D * sizeof(unsigned short); // 38.4 MB
    size_t NI4  = ((size_t)(N + 1) * sizeof(int) + 15) & ~15ull;
    size_t L4   = ((size_t)L * sizeof(int) + 15) & ~15ull;
    size_t Npad = ((size_t)N + 15) & ~15ull;
    char* w = (char*)d_ws;
    int*   flags   = (int*)w;                        // 3 ints
    float* reg     = (float*)(w + 64);               // 1 float
    float* uacc    = (float*)(w + 256);
    float* pacc    = (float*)(w + 256 + BACC);
    float* nacc    = (float*)(w + 256 + 2 * BACC);
    char*  q       = w + 256 + 3 * BACC;
    float* regp    = (float*)q;             q += (size_t)B * sizeof(float);
    int*   row_ptr = (int*)q;               q += NI4;
    uint2* part    = (uint2*)q;             q += (size_t)E * sizeof(uint2);   // 16 MB
    int*   bcnt    = (int*)q;               q += L4;                          // 573 KB
    int*   bsums   = (int*)q;               q += 1024;
    int*   boffs   = (int*)q;               q += 1024;
    unsigned char* flag3 = (unsigned char*)q; q += Npad;                      // 150 KB
    unsigned char* flag2 = (unsigned char*)q; q += Npad;                      // 150 KB
    unsigned int* sedge = (unsigned int*)q; q += (size_t)E * sizeof(unsigned int); // 8 MB
    unsigned short* Atab = (unsigned short*)q;  q += NT;
    unsigned short* Btab = (unsigned short*)q;
    // total ~114 MB (prev session proved ws >= 166 MB)

    long total = (long)N * EMB_D;        // 19.2M
    long nuf   = (long)NU * EMB_D;
    const int thr = 256;
    float* out = (float*)d_out;

    k_detect<<<3, 64, 0, stream>>>((const unsigned short*)ue, (const unsigned short*)ie,
                                   (const unsigned short*)ev, flags);
    k_build_emb<<<(unsigned)((total / 4 + thr - 1) / thr), thr, 0, stream>>>(ue, ie, flags, Atab, nuf, total);
    k_init_acc<<<B, EMB_D, 0, stream>>>(ue, ie, flags, user, pos, neg, NU, NI,
                                        uacc, pacc, nacc, regp);
    k_reduce_reg<<<1, 256, 0, stream>>>(regp, reg, B);

    // Frontier flags: flag3 = batch nodes; flag2 = batch + in-nbrs of flag3.
    int fwords = (int)((2 * Npad) / 4);
    k_zero_flags<<<(fwords + thr - 1) / thr, thr, 0, stream>>>((int*)flag3, fwords);
    k_mark_batch<<<(B + thr - 1) / thr, thr, 0, stream>>>(user, pos, neg, NU, NI, B,
                                                          flag3, flag2);

    // CSR build: two-level LDS partition, no global atomics.
    k_part_count<<<NBp, 256, 0, stream>>>(erow, bcnt, E, N, nbuck, NBp);
    k_gscan1<<<nbL, 256, 0, stream>>>(bcnt, bsums, L);
    k_gscan2<<<1, 256, 0, stream>>>(bsums, boffs, nbL, row_ptr + N);
    k_gscan3<<<nbL, 256, 0, stream>>>(bcnt, boffs, L);
    k_part_scatter<<<NBp, 256, 0, stream>>>(erow, ecol, ev, flags, bcnt, part, E, N, nbuck, NBp);
    k_build_csr<<<nbuck, 256, 0, stream>>>(part, bcnt, row_ptr, sedge, E, N, NBp, nbuck);

    // flag2 |= in-neighbors of flag3 rows (needs CSR).
    k_mark_nbrs<<<(N + thr - 1) / thr, thr, 0, stream>>>(row_ptr, sedge, flag3, flag2, N);

    int rows_per_block = thr / 64;                       // 4
    int sgrid = (N + rows_per_block - 1) / rows_per_block;  // 37500

    // Layer 1: Atab -> Btab (full)
    k_spmm_csr<<<sgrid, thr, 0, stream>>>(Atab, Btab, row_ptr, sedge, N, flag2, 0);
    k_gather_add<<<B, EMB_D, 0, stream>>>(Btab, user, pos, neg, uacc, pacc, nacc, NU, NI);
    // Layer 2: Btab -> Atab (rows needed by layer 3 + batch)
    k_spmm_csr<<<sgrid, thr, 0, stream>>>(Btab, Atab, row_ptr, sedge, N, flag2, 1);
    k_gather_add<<<B, EMB_D, 0, stream>>>(Atab, user, pos, neg, uacc, pacc, nacc, NU, NI);
    // Layer 3: Atab -> Btab (batch rows only)
    k_spmm_csr<<<sgrid, thr, 0, stream>>>(Atab, Btab, row_ptr, sedge, N, flag3, 1);
    k_gather_add<<<B, EMB_D, 0, stream>>>(Btab, user, pos, neg, uacc, pacc, nacc, NU, NI);

    k_final<<<B, 64, 0, stream>>>(uacc, pacc, nacc, reg, out);
}

// Round 4
// 442.801 us; speedup vs baseline: 1.5063x; 1.0558x over previous
//
#include <hip/hip_runtime.h>
#include <hip/hip_bf16.h>

#define EMB_D 128
#define BSH 9          // rows per coarse bucket = 512
#define MAXBUCK 512    // nbuck = ceil(N/512) must be <= 512 (N <= 262144)
#define CHUNKP 4096    // edges per partition block

#if defined(__has_builtin)
#if __has_builtin(__builtin_amdgcn_cvt_pk_f32_fp8) && \
    __has_builtin(__builtin_amdgcn_cvt_pk_fp8_f32) && \
    __has_builtin(__builtin_amdgcn_cvt_f32_fp8)
#define FP8_HW 1
#endif
#endif
#ifndef FP8_HW
#define FP8_HW 0
#endif

typedef float f32x2 __attribute__((ext_vector_type(2)));

__device__ __forceinline__ float bf16_raw_to_f(unsigned short h) {
    return __uint_as_float(((unsigned int)h) << 16);
}
__device__ __forceinline__ float sane(float v) {
    return (v == v && fabsf(v) < 256.0f) ? v : 0.0f;
}
__device__ __forceinline__ float load_f(const void* p, int isf32, size_t idx) {
    return isf32 ? ((const float*)p)[idx]
                 : bf16_raw_to_f(((const unsigned short*)p)[idx]);
}

// ---------- fp8 e4m3fn helpers (HW cvt on gfx950, SW fallback otherwise) ----
#if !FP8_HW
__device__ __forceinline__ float fp8_dec1(unsigned int b) {
    unsigned int s = (b >> 7) & 1u, e = (b >> 3) & 15u, m = b & 7u;
    float v;
    if (e == 0) v = (float)m * 0.001953125f;                       // 2^-9 step
    else        v = __uint_as_float(((e + 120u) << 23) | (m << 20));
    if (e == 15u && m == 7u) v = 0.0f;                             // NaN -> 0
    return s ? -v : v;
}
__device__ __forceinline__ unsigned int fp8_enc1(float f) {
    unsigned int s = ((__float_as_uint(f) >> 31) & 1u) << 7;
    float af = fabsf(f);
    if (!(af == af)) return 0u;
    if (af == 0.0f) return s;
    if (af >= 448.0f) return s | 0x7Eu;                            // e=15,m=6
    if (af < 0.015625f) {                                          // subnormal
        int q = (int)rintf(af * 512.0f);
        if (q >= 8) return s | 0x08u;
        return s | (unsigned int)q;
    }
    unsigned int u = __float_as_uint(af);
    unsigned int E = (u >> 23) & 255u;
    unsigned int man = u & 0x7FFFFFu;
    unsigned int r = man + 0x7FFFFu + ((man >> 20) & 1u);          // RNE to 3b
    if (r >= 0x800000u) { E += 1u; r = 0u; }
    unsigned int m3 = (r >> 20) & 7u;
    unsigned int e4 = E - 120u;
    if (e4 >= 15u && m3 >= 7u) { e4 = 15u; m3 = 6u; }
    return s | (e4 << 3) | m3;
}
#endif

__device__ __forceinline__ void fp8x4_dec(unsigned int w, float* o) {
#if FP8_HW
    f32x2 lo = __builtin_amdgcn_cvt_pk_f32_fp8(w, false);
    f32x2 hi = __builtin_amdgcn_cvt_pk_f32_fp8(w, true);
    o[0] = lo.x; o[1] = lo.y; o[2] = hi.x; o[3] = hi.y;
#else
    o[0] = fp8_dec1(w & 255u);        o[1] = fp8_dec1((w >> 8) & 255u);
    o[2] = fp8_dec1((w >> 16) & 255u); o[3] = fp8_dec1(w >> 24);
#endif
}
__device__ __forceinline__ unsigned int fp8x4_enc(float a, float b, float c, float d) {
#if FP8_HW
    unsigned int p = 0;
    p = __builtin_amdgcn_cvt_pk_fp8_f32(a, b, p, false);
    p = __builtin_amdgcn_cvt_pk_fp8_f32(c, d, p, true);
    return p;
#else
    return fp8_enc1(a) | (fp8_enc1(b) << 8) | (fp8_enc1(c) << 16) | (fp8_enc1(d) << 24);
#endif
}
__device__ __forceinline__ float fp8_dec_byte(unsigned int b) {
#if FP8_HW
    return __builtin_amdgcn_cvt_f32_fp8(b, 0);
#else
    return fp8_dec1(b);
#endif
}

// flags[a]=1 if array a is stored fp32, 0 if bf16 (insurance; expect all 1).
__global__ void k_detect(const unsigned short* __restrict__ ue,
                         const unsigned short* __restrict__ ie,
                         const unsigned short* __restrict__ ev,
                         int* __restrict__ flags) {
    int a = blockIdx.x;
    const unsigned short* p = (a == 0) ? ue : (a == 1) ? ie : ev;
    int lane = threadIdx.x;
    int cnt = 0;
    #pragma unroll
    for (int k = 0; k < 16; ++k) {
        float v = bf16_raw_to_f(p[k * 64 + lane]);
        if (!(fabsf(v) < 1.0f)) cnt++;
    }
    #pragma unroll
    for (int off = 32; off > 0; off >>= 1)
        cnt += __shfl_down(cnt, off, 64);
    if (lane == 0) flags[a] = (cnt > 64) ? 1 : 0;
}

// Canonical fp8 table T[N,128] + per-row scale S[N]. 32 lanes per row.
__global__ __launch_bounds__(256) void k_build_emb8(
        const void* __restrict__ ue, const void* __restrict__ ie,
        const int* __restrict__ flags,
        unsigned char* __restrict__ T, float* __restrict__ S,
        int NU, int N) {
    int gid = blockIdx.x * blockDim.x + threadIdx.x;
    int row = gid >> 5;
    if (row >= N) return;
    int l = gid & 31;
    const void* src; long r; int f;
    if (row < NU) { src = ue; r = row;      f = flags[0]; }
    else          { src = ie; r = row - NU; f = flags[1]; }
    float v0, v1, v2, v3;
    if (f) {
        float4 t = ((const float4*)src)[r * 32 + l];
        v0 = sane(t.x); v1 = sane(t.y); v2 = sane(t.z); v3 = sane(t.w);
    } else {
        ushort4 t = ((const ushort4*)src)[r * 32 + l];
        v0 = sane(bf16_raw_to_f(t.x)); v1 = sane(bf16_raw_to_f(t.y));
        v2 = sane(bf16_raw_to_f(t.z)); v3 = sane(bf16_raw_to_f(t.w));
    }
    float m = fmaxf(fmaxf(fabsf(v0), fabsf(v1)), fmaxf(fabsf(v2), fabsf(v3)));
    #pragma unroll
    for (int off = 1; off < 32; off <<= 1)
        m = fmaxf(m, __shfl_xor(m, off, 64));
    float enc = (m > 0.0f) ? 448.0f / m : 0.0f;
    ((unsigned int*)T)[(size_t)row * 32 + l] =
        fp8x4_enc(v0 * enc, v1 * enc, v2 * enc, v3 * enc);
    if (l == 0) S[row] = (m > 0.0f) ? m * (1.0f / 448.0f) : 0.0f;
}

// Layer-0 gather (fp32 from ORIGINAL inputs) into accumulators.
__global__ void k_init_acc(const void* __restrict__ ue, const void* __restrict__ ie,
                           const int* __restrict__ flags,
                           const int* __restrict__ user, const int* __restrict__ pos,
                           const int* __restrict__ neg, int NU, int NI,
                           float* __restrict__ uacc, float* __restrict__ pacc,
                           float* __restrict__ nacc, float* __restrict__ regp) {
    __shared__ float sred[2];
    int b = blockIdx.x;
    int d = threadIdx.x;   // 0..127
    int ui = min(max(user[b], 0), NU - 1);
    int pi = min(max(pos[b],  0), NI - 1);
    int ni = min(max(neg[b],  0), NI - 1);
    int f0 = flags[0], f1 = flags[1];
    float u = sane(load_f(ue, f0, (size_t)ui * EMB_D + d));
    float p = sane(load_f(ie, f1, (size_t)pi * EMB_D + d));
    float n = sane(load_f(ie, f1, (size_t)ni * EMB_D + d));
    size_t o = (size_t)b * EMB_D + d;
    uacc[o] = u;
    pacc[o] = p;
    nacc[o] = n;
    float s = fabsf(u) + fabsf(p) + fabsf(n);
    #pragma unroll
    for (int off = 32; off > 0; off >>= 1)
        s += __shfl_down(s, off, 64);
    if ((d & 63) == 0) sred[d >> 6] = s;
    __syncthreads();
    if (d == 0) regp[b] = sred[0] + sred[1];
}

// Reduce regp[B] -> reg[0]. Single block.
__global__ void k_reduce_reg(const float* __restrict__ regp, float* __restrict__ reg, int B) {
    __shared__ float ss[256];
    int t = threadIdx.x;
    float s = 0.0f;
    for (int i = t; i < B; i += 256) s += regp[i];
    ss[t] = s;
    __syncthreads();
    for (int off = 128; off > 0; off >>= 1) {
        if (t < off) ss[t] += ss[t + off];
        __syncthreads();
    }
    if (t == 0) reg[0] = ss[0];
}

// ---------- CSR build, transaction-efficient two-level partition ----------

__global__ __launch_bounds__(256) void k_part_count(const int* __restrict__ erow,
        int* __restrict__ bcnt, int E, int N, int nbuck, int NB) {
    __shared__ int lh[MAXBUCK];
    int b = blockIdx.x, t = threadIdx.x;
    for (int i = t; i < MAXBUCK; i += 256) lh[i] = 0;
    __syncthreads();
    int beg = b * CHUNKP;
    int cnt = min(CHUNKP, E - beg);
    for (int p = t; p < cnt; p += 256) {
        int r = min(max(erow[beg + p], 0), N - 1);
        atomicAdd(&lh[r >> BSH], 1);
    }
    __syncthreads();
    for (int i = t; i < nbuck; i += 256) bcnt[(long)i * NB + b] = lh[i];
}

// Generic 3-phase exclusive scan over int array a[L] (in place).
__global__ void k_gscan1(const int* __restrict__ a, int* __restrict__ bsums, int L) {
    __shared__ int ss[256];
    int t = threadIdx.x;
    int base = blockIdx.x * 1024 + t * 4;
    int s = 0;
    #pragma unroll
    for (int j = 0; j < 4; ++j) {
        int idx = base + j;
        if (idx < L) s += a[idx];
    }
    ss[t] = s;
    __syncthreads();
    for (int off = 128; off > 0; off >>= 1) {
        if (t < off) ss[t] += ss[t + off];
        __syncthreads();
    }
    if (t == 0) bsums[blockIdx.x] = ss[0];
}

__global__ void k_gscan2(const int* __restrict__ bsums, int* __restrict__ boffs,
                         int nb, int* __restrict__ rowptrN) {
    __shared__ int ss[256];
    int t = threadIdx.x;
    int s = (t < nb) ? bsums[t] : 0;
    ss[t] = s;
    __syncthreads();
    for (int off = 1; off < 256; off <<= 1) {
        int v = (t >= off) ? ss[t - off] : 0;
        __syncthreads();
        ss[t] += v;
        __syncthreads();
    }
    if (t < nb) boffs[t] = ss[t] - s;       // exclusive
    if (t == 255) *rowptrN = ss[255];       // total E -> row_ptr[N]
}

__global__ void k_gscan3(int* __restrict__ a, const int* __restrict__ boffs, int L) {
    __shared__ int ss[256];
    int t = threadIdx.x;
    int base = blockIdx.x * 1024 + t * 4;
    int c[4];
    int s = 0;
    #pragma unroll
    for (int j = 0; j < 4; ++j) {
        int idx = base + j;
        c[j] = (idx < L) ? a[idx] : 0;
        s += c[j];
    }
    ss[t] = s;
    __syncthreads();
    for (int off = 1; off < 256; off <<= 1) {
        int v = (t >= off) ? ss[t - off] : 0;
        __syncthreads();
        ss[t] += v;
        __syncthreads();
    }
    int run = boffs[blockIdx.x] + ss[t] - s;
    #pragma unroll
    for (int j = 0; j < 4; ++j) {
        int idx = base + j;
        if (idx < L) a[idx] = run;
        run += c[j];
    }
}

__global__ __launch_bounds__(256) void k_part_scatter(
        const int* __restrict__ erow, const int* __restrict__ ecol,
        const void* __restrict__ eval, const int* __restrict__ flags,
        const int* __restrict__ boff, uint2* __restrict__ part,
        int E, int N, int nbuck, int NB) {
    __shared__ uint2 lrec[CHUNKP];            // 32 KB
    __shared__ unsigned short lidx[CHUNKP];   // 8 KB
    __shared__ int hist[MAXBUCK];             // 2 KB (hist -> cursor -> delta)
    __shared__ int bstart[MAXBUCK];           // 2 KB
    __shared__ int ss[256];
    int b = blockIdx.x, t = threadIdx.x;
    int beg = b * CHUNKP;
    int cnt = min(CHUNKP, E - beg);
    for (int i = t; i < MAXBUCK; i += 256) hist[i] = 0;
    __syncthreads();
    int f2 = flags[2];
    for (int p = t; p < cnt; p += 256) {
        int e = beg + p;
        int r = min(max(erow[e], 0), N - 1);
        int c = min(max(ecol[e], 0), N - 1);
        float v = sane(load_f(eval, f2, e));
        if (v < 0.0f) v = 0.0f;
        unsigned int u = __float_as_uint(v);
        unsigned int vb = ((u + 0x10000u) >> 17) & 0x3FFFu;   // exp8 + man6
        lrec[p] = make_uint2((unsigned int)r, ((unsigned int)c << 14) | vb);
        atomicAdd(&hist[r >> BSH], 1);
    }
    __syncthreads();
    int c0 = hist[2 * t], c1 = hist[2 * t + 1];
    int s = c0 + c1;
    ss[t] = s;
    __syncthreads();
    for (int off = 1; off < 256; off <<= 1) {
        int v = (t >= off) ? ss[t - off] : 0;
        __syncthreads();
        ss[t] += v;
        __syncthreads();
    }
    int eb = ss[t] - s;
    bstart[2 * t] = eb;
    bstart[2 * t + 1] = eb + c0;
    hist[2 * t] = eb;              // cursor = bstart
    hist[2 * t + 1] = eb + c0;
    __syncthreads();
    for (int p = t; p < cnt; p += 256) {
        int bin = (int)(lrec[p].x >> BSH);
        int pos = atomicAdd(&hist[bin], 1);
        lidx[pos] = (unsigned short)p;
    }
    __syncthreads();
    for (int i = t; i < nbuck; i += 256)
        hist[i] = boff[(long)i * NB + b] - bstart[i];
    __syncthreads();
    for (int p = t; p < cnt; p += 256) {
        uint2 rec = lrec[lidx[p]];
        int bin = (int)(rec.x >> BSH);
        part[hist[bin] + p] = rec;
    }
}

__global__ __launch_bounds__(256) void k_build_csr(
        const uint2* __restrict__ part, const int* __restrict__ boff,
        int* __restrict__ row_ptr, unsigned int* __restrict__ sedge,
        int E, int N, int NB, int nbuck) {
    __shared__ int rcnt[512];
    __shared__ int rstart[512];
    __shared__ int rcur[512];
    __shared__ int ss[256];
    int bin = blockIdx.x, t = threadIdx.x;
    int base = boff[(long)bin * NB];
    int next = (bin + 1 < nbuck) ? boff[(long)(bin + 1) * NB] : E;
    int cnt = next - base;
    int r0 = bin << BSH;
    int nrows = min(512, N - r0);
    rcnt[2 * t] = 0; rcnt[2 * t + 1] = 0;
    __syncthreads();
    for (int i = t; i < cnt; i += 256)
        atomicAdd(&rcnt[part[base + i].x - r0], 1);
    __syncthreads();
    int c0 = rcnt[2 * t], c1 = rcnt[2 * t + 1];
    int s = c0 + c1;
    ss[t] = s;
    __syncthreads();
    for (int off = 1; off < 256; off <<= 1) {
        int v = (t >= off) ? ss[t - off] : 0;
        __syncthreads();
        ss[t] += v;
        __syncthreads();
    }
    int eb = ss[t] - s;
    rstart[2 * t] = eb; rstart[2 * t + 1] = eb + c0;
    rcur[2 * t]   = eb; rcur[2 * t + 1]   = eb + c0;
    __syncthreads();
    for (int j = t; j < nrows; j += 256)
        row_ptr[r0 + j] = base + rstart[j];
    for (int i = t; i < cnt; i += 256) {
        uint2 rec = part[base + i];
        int pos = atomicAdd(&rcur[rec.x - r0], 1);
        sedge[base + pos] = rec.y;
    }
}

// ---------- Frontier marking (backward pruning, bit-exact) ----------

__global__ void k_zero_flags(int* __restrict__ f, int words) {
    int i = blockIdx.x * blockDim.x + threadIdx.x;
    if (i < words) f[i] = 0;
}

__global__ void k_mark_batch(const int* __restrict__ user, const int* __restrict__ pos,
                             const int* __restrict__ neg, int NU, int NI, int B,
                             unsigned char* __restrict__ flag3,
                             unsigned char* __restrict__ flag2) {
    int b = blockIdx.x * blockDim.x + threadIdx.x;
    if (b >= B) return;
    int ui = min(max(user[b], 0), NU - 1);
    int pi = NU + min(max(pos[b], 0), NI - 1);
    int ni = NU + min(max(neg[b], 0), NI - 1);
    flag3[ui] = 1; flag3[pi] = 1; flag3[ni] = 1;
    flag2[ui] = 1; flag2[pi] = 1; flag2[ni] = 1;
}

__global__ void k_mark_nbrs(const int* __restrict__ row_ptr,
                            const unsigned int* __restrict__ sedge,
                            const unsigned char* __restrict__ flag3,
                            unsigned char* __restrict__ flag2, int N) {
    int r = blockIdx.x * blockDim.x + threadIdx.x;
    if (r >= N || !flag3[r]) return;
    int beg = row_ptr[r], end = row_ptr[r + 1];
    for (int i = beg; i < end; ++i)
        flag2[sedge[i] >> 14] = 1;
}

// ---------- SpMM (fp8 in / fp8 out, per-row scales) + tail ----------

// One wave per dst row; 8 subgroups of 8 lanes each process every 8th edge;
// lane sl covers fp8 bytes [16*sl, 16*sl+15] (one uint4) of the 128B row.
__global__ void k_spmm_csr8(const unsigned char* __restrict__ T,
                            const float* __restrict__ S,
                            unsigned char* __restrict__ Td,
                            float* __restrict__ Sd,
                            const int* __restrict__ row_ptr,
                            const unsigned int* __restrict__ sedge, int N,
                            const unsigned char* __restrict__ skipf, int use_skip) {
    int row = blockIdx.x * (blockDim.x >> 6) + (threadIdx.x >> 6);
    if (row >= N) return;
    if (use_skip && skipf[row] == 0) return;
    int lane = threadIdx.x & 63;
    int sub = lane >> 3;         // 0..7: edge phase
    int sl  = lane & 7;          // 16B chunk of the row
    int beg = row_ptr[row], end = row_ptr[row + 1];
    float a[16];
    #pragma unroll
    for (int j = 0; j < 16; ++j) a[j] = 0.0f;
    for (int i = beg + sub; i < end; i += 8) {
        unsigned int se = sedge[i];
        unsigned int c = se >> 14;
        float v = __uint_as_float((se & 0x3FFFu) << 17);
        float vs = v * S[c];
        uint4 h = ((const uint4*)(T + (size_t)c * EMB_D))[sl];
        float d[4];
        fp8x4_dec(h.x, d);
        a[0] += vs * d[0]; a[1] += vs * d[1]; a[2] += vs * d[2]; a[3] += vs * d[3];
        fp8x4_dec(h.y, d);
        a[4] += vs * d[0]; a[5] += vs * d[1]; a[6] += vs * d[2]; a[7] += vs * d[3];
        fp8x4_dec(h.z, d);
        a[8] += vs * d[0]; a[9] += vs * d[1]; a[10] += vs * d[2]; a[11] += vs * d[3];
        fp8x4_dec(h.w, d);
        a[12] += vs * d[0]; a[13] += vs * d[1]; a[14] += vs * d[2]; a[15] += vs * d[3];
    }
    #pragma unroll
    for (int j = 0; j < 16; ++j) {
        a[j] += __shfl_xor(a[j], 8, 64);
        a[j] += __shfl_xor(a[j], 16, 64);
        a[j] += __shfl_xor(a[j], 32, 64);
    }
    // row absmax (a[] identical across subgroups; xor over sl bits 0..2)
    float m = 0.0f;
    #pragma unroll
    for (int j = 0; j < 16; ++j) m = fmaxf(m, fabsf(a[j]));
    m = fmaxf(m, __shfl_xor(m, 1, 64));
    m = fmaxf(m, __shfl_xor(m, 2, 64));
    m = fmaxf(m, __shfl_xor(m, 4, 64));
    if (sub == 0) {
        float enc = (m > 0.0f) ? 448.0f / m : 0.0f;
        uint4 w;
        w.x = fp8x4_enc(a[0] * enc,  a[1] * enc,  a[2] * enc,  a[3] * enc);
        w.y = fp8x4_enc(a[4] * enc,  a[5] * enc,  a[6] * enc,  a[7] * enc);
        w.z = fp8x4_enc(a[8] * enc,  a[9] * enc,  a[10] * enc, a[11] * enc);
        w.w = fp8x4_enc(a[12] * enc, a[13] * enc, a[14] * enc, a[15] * enc);
        ((uint4*)(Td + (size_t)row * EMB_D))[sl] = w;
        if (lane == 0) Sd[row] = (m > 0.0f) ? m * (1.0f / 448.0f) : 0.0f;
    }
}

// Accumulate this layer's rows (fp8 table + scale) at batch indices.
__global__ void k_gather_add8(const unsigned char* __restrict__ T,
                              const float* __restrict__ S,
                              const int* __restrict__ user, const int* __restrict__ pos,
                              const int* __restrict__ neg,
                              float* __restrict__ uacc, float* __restrict__ pacc,
                              float* __restrict__ nacc, int NU, int NI) {
    int b = blockIdx.x;
    int d = threadIdx.x;   // 0..127
    int ui = min(max(user[b], 0), NU - 1);
    int pi = NU + min(max(pos[b], 0), NI - 1);
    int ni = NU + min(max(neg[b], 0), NI - 1);
    size_t o = (size_t)b * EMB_D + d;
    uacc[o] += fp8_dec_byte(T[(size_t)ui * EMB_D + d]) * S[ui];
    pacc[o] += fp8_dec_byte(T[(size_t)pi * EMB_D + d]) * S[pi];
    nacc[o] += fp8_dec_byte(T[(size_t)ni * EMB_D + d]) * S[ni];
}

// One wave per batch element: dots, softplus, + reg; fp32 store.
__global__ void k_final(const float* __restrict__ uacc, const float* __restrict__ pacc,
                        const float* __restrict__ nacc, const float* __restrict__ reg,
                        float* __restrict__ out) {
    int b = blockIdx.x;
    int l = threadIdx.x;   // 0..63
    const float2* u2 = (const float2*)(uacc + (size_t)b * EMB_D);
    const float2* p2 = (const float2*)(pacc + (size_t)b * EMB_D);
    const float2* n2 = (const float2*)(nacc + (size_t)b * EMB_D);
    float2 u = u2[l], p = p2[l], n = n2[l];
    float ps = u.x * p.x + u.y * p.y;
    float ns = u.x * n.x + u.y * n.y;
    #pragma unroll
    for (int off = 32; off > 0; off >>= 1) {
        ps += __shfl_down(ps, off, 64);
        ns += __shfl_down(ns, off, 64);
    }
    if (l == 0) {
        // latents are acc/4 -> scores scale by 1/16
        float x = (ns - ps) * 0.0625f;
        float sp = fmaxf(x, 0.0f) + log1pf(expf(-fabsf(x)));
        out[b] = sp + 1e-4f * reg[0];
    }
}

extern "C" void kernel_launch(void* const* d_in, const int* in_sizes, int n_in,
                              void* d_out, int out_size, void* d_ws, size_t ws_size,
                              hipStream_t stream) {
    const void* ue   = d_in[0];
    const void* ie   = d_in[1];
    const int*  erow = (const int*)d_in[2];
    const int*  ecol = (const int*)d_in[3];
    const void* ev   = d_in[4];
    const int*  user = (const int*)d_in[5];
    const int*  pos  = (const int*)d_in[6];
    const int*  neg  = (const int*)d_in[7];

    int NU = in_sizes[0] / EMB_D;        // 100000
    int NI = in_sizes[1] / EMB_D;        // 50000
    int N  = NU + NI;                    // 150000
    int E  = in_sizes[2];                // 2000000
    int B  = in_sizes[5];                // 8192

    int nbuck = (N + ((1 << BSH) - 1)) >> BSH;   // 293 (must be <= MAXBUCK)
    int NBp   = (E + CHUNKP - 1) / CHUNKP;       // 489 partition blocks
    int L     = nbuck * NBp;                     // 143277
    int nbL   = (L + 1023) / 1024;               // 140 (<= 256)

    // Workspace layout (all 16B-aligned):
    size_t BACC = (size_t)B * EMB_D * sizeof(float);           // 4 MB
    size_t T8   = (size_t)N * EMB_D;                           // 19.2 MB (fp8)
    size_t SC   = (((size_t)N * sizeof(float)) + 15) & ~15ull; // 600 KB
    size_t NI4  = ((size_t)(N + 1) * sizeof(int) + 15) & ~15ull;
    size_t L4   = ((size_t)L * sizeof(int) + 15) & ~15ull;
    size_t Npad = ((size_t)N + 15) & ~15ull;
    char* w = (char*)d_ws;
    int*   flags   = (int*)w;                        // 3 ints
    float* reg     = (float*)(w + 64);               // 1 float
    float* uacc    = (float*)(w + 256);
    float* pacc    = (float*)(w + 256 + BACC);
    float* nacc    = (float*)(w + 256 + 2 * BACC);
    char*  q       = w + 256 + 3 * BACC;
    float* regp    = (float*)q;             q += (size_t)B * sizeof(float);
    int*   row_ptr = (int*)q;               q += NI4;
    uint2* part    = (uint2*)q;             q += (size_t)E * sizeof(uint2);   // 16 MB
    int*   bcnt    = (int*)q;               q += L4;                          // 573 KB
    int*   bsums   = (int*)q;               q += 1024;
    int*   boffs   = (int*)q;               q += 1024;
    unsigned char* flag3 = (unsigned char*)q; q += Npad;                      // 150 KB
    unsigned char* flag2 = (unsigned char*)q; q += Npad;                      // 150 KB
    unsigned int* sedge = (unsigned int*)q; q += (size_t)E * sizeof(unsigned int); // 8 MB
    unsigned char* Ta = (unsigned char*)q;  q += T8;
    float*         Sa = (float*)q;          q += SC;
    unsigned char* Tb = (unsigned char*)q;  q += T8;
    float*         Sb = (float*)q;
    // total ~78 MB (prev session proved ws >= 166 MB)

    const int thr = 256;
    float* out = (float*)d_out;

    k_detect<<<3, 64, 0, stream>>>((const unsigned short*)ue, (const unsigned short*)ie,
                                   (const unsigned short*)ev, flags);
    k_build_emb8<<<(N * 32 + thr - 1) / thr, thr, 0, stream>>>(ue, ie, flags, Ta, Sa, NU, N);
    k_init_acc<<<B, EMB_D, 0, stream>>>(ue, ie, flags, user, pos, neg, NU, NI,
                                        uacc, pacc, nacc, regp);
    k_reduce_reg<<<1, 256, 0, stream>>>(regp, reg, B);

    // Frontier flags: flag3 = batch nodes; flag2 = batch + in-nbrs of flag3.
    int fwords = (int)((2 * Npad) / 4);
    k_zero_flags<<<(fwords + thr - 1) / thr, thr, 0, stream>>>((int*)flag3, fwords);
    k_mark_batch<<<(B + thr - 1) / thr, thr, 0, stream>>>(user, pos, neg, NU, NI, B,
                                                          flag3, flag2);

    // CSR build: two-level LDS partition, no global atomics.
    k_part_count<<<NBp, 256, 0, stream>>>(erow, bcnt, E, N, nbuck, NBp);
    k_gscan1<<<nbL, 256, 0, stream>>>(bcnt, bsums, L);
    k_gscan2<<<1, 256, 0, stream>>>(bsums, boffs, nbL, row_ptr + N);
    k_gscan3<<<nbL, 256, 0, stream>>>(bcnt, boffs, L);
    k_part_scatter<<<NBp, 256, 0, stream>>>(erow, ecol, ev, flags, bcnt, part, E, N, nbuck, NBp);
    k_build_csr<<<nbuck, 256, 0, stream>>>(part, bcnt, row_ptr, sedge, E, N, NBp, nbuck);

    // flag2 |= in-neighbors of flag3 rows (needs CSR).
    k_mark_nbrs<<<(N + thr - 1) / thr, thr, 0, stream>>>(row_ptr, sedge, flag3, flag2, N);

    int rows_per_block = thr / 64;                       // 4
    int sgrid = (N + rows_per_block - 1) / rows_per_block;  // 37500

    // Layer 1: Ta -> Tb (full)
    k_spmm_csr8<<<sgrid, thr, 0, stream>>>(Ta, Sa, Tb, Sb, row_ptr, sedge, N, flag2, 0);
    k_gather_add8<<<B, EMB_D, 0, stream>>>(Tb, Sb, user, pos, neg, uacc, pacc, nacc, NU, NI);
    // Layer 2: Tb -> Ta (rows needed by layer 3 + batch)
    k_spmm_csr8<<<sgrid, thr, 0, stream>>>(Tb, Sb, Ta, Sa, row_ptr, sedge, N, flag2, 1);
    k_gather_add8<<<B, EMB_D, 0, stream>>>(Ta, Sa, user, pos, neg, uacc, pacc, nacc, NU, NI);
    // Layer 3: Ta -> Tb (batch rows only)
    k_spmm_csr8<<<sgrid, thr, 0, stream>>>(Ta, Sa, Tb, Sb, row_ptr, sedge, N, flag3, 1);
    k_gather_add8<<<B, EMB_D, 0, stream>>>(Tb, Sb, user, pos, neg, uacc, pacc, nacc, NU, NI);

    k_final<<<B, 64, 0, stream>>>(uacc, pacc, nacc, reg, out);
}